// Round 4
// baseline (1219.483 us; speedup 1.0000x reference)
//
#include <hip/hip_runtime.h>
#include <cstdint>
#include <cstddef>

// Problem constants (B=32, M=4096, DIMS=512, LENGTH=64, HEADS=8, HD=64)
#define EPS_LN 1e-5f

typedef _Float16 half8 __attribute__((ext_vector_type(8)));  // MFMA A/B frag
typedef float f32x4 __attribute__((ext_vector_type(4)));

__device__ __forceinline__ uint16_t h16(float f) {
  _Float16 h = (_Float16)f;                    // v_cvt_f16_f32 (RNE)
  return __builtin_bit_cast(uint16_t, h);
}
__device__ __forceinline__ uint32_t packh2(float a, float b) {
  return (uint32_t)h16(a) | ((uint32_t)h16(b) << 16);
}

// ---------------------------------------------------------------------------
// Kernel 0: prep weights into workspace (fp16 bit-pattern uint16 arrays)
//   QW[h][w][d] = sum_j q[w,h,j] * fc_w[h*128+j, d]   (k-proj folded into q;
//                 k-bias cancels in softmax over m)
//   WV[h][j][d] = fc_w[h*128+64+j, d]
//   FC2[d][e]   = fcfc_w[d, e]
// ---------------------------------------------------------------------------
__global__ __launch_bounds__(512) void prep_kernel(
    const float* __restrict__ q, const float* __restrict__ fc_w,
    const float* __restrict__ fcfc_w,
    uint16_t* __restrict__ qw, uint16_t* __restrict__ wv,
    uint16_t* __restrict__ fc2) {
  int t = blockIdx.x * 512 + threadIdx.x;     // grid = 1536*512 = 3*2^18
  int sec = t >> 18;
  int idx = t & 262143;
  if (sec == 0) {
    int h = idx >> 15, w = (idx >> 9) & 63, d = idx & 511;
    float s = 0.f;
#pragma unroll 8
    for (int j = 0; j < 64; ++j)
      s += q[(w * 8 + h) * 64 + j] * fc_w[(h * 128 + j) * 512 + d];
    qw[idx] = h16(s);
  } else if (sec == 1) {
    int h = idx >> 15, j = (idx >> 9) & 63, d = idx & 511;
    wv[idx] = h16(fc_w[(h * 128 + 64 + j) * 512 + d]);
  } else {
    fc2[idx] = h16(fcfc_w[idx]);
  }
}

// Select-shuffle: shuffle both candidate regs, pick by (lane>=32).
__device__ __forceinline__ uint32_t selshfl(uint32_t lo, uint32_t hi, int src,
                                            bool sel_hi) {
  uint32_t a = (uint32_t)__shfl((int)lo, src);
  uint32_t b = (uint32_t)__shfl((int)hi, src);
  return sel_hi ? b : a;
}

// ---------------------------------------------------------------------------
// Kernel 1: fused projection + flash attention (fp16 MFMA, fp32 accum).
// Grid 256 = (b<<3)|chunk ; 512 threads = 8 waves, wave == head.
// Per 64-row m sub-tile (order: S GEMM -> softmax -> V GEMM -> PV), with
// async-STAGE split (T14): next tile's loads issued at the two LOWEST
// register-pressure points (pfA after S GEMM, pfB after v2 pack) so peak
// live VGPR at PV stays ~240 < 256 (no spill at 8 waves/CU).
// Fragment maps (m89-verified, dtype-independent):
//   C: row=(l>>4)*4+reg, col=l&15. A: row=l&15, k=8*(l>>4)+i.
//   B: k=8*(l>>4)+i, col=l&15.
// PV re-layout (desk-checked): for target m = kk*32+8*g+i,
//   src lane = (2*(g&1)+(i>>2))*16 + l15, block mi = 2*kk+(g>>1),
//   packed pair = (i&3)>>1  -> selshfl(p2[2kk][..], p2[2kk+1][..], s0(+16)).
// ---------------------------------------------------------------------------
__global__ __launch_bounds__(512) void fused_attn(
    const float* __restrict__ x, const uint16_t* __restrict__ qw,
    const uint16_t* __restrict__ wv, float* __restrict__ pacc,
    float* __restrict__ pm, float* __restrict__ pl) {
  __shared__ __align__(16) uint8_t xs[64 * 512 * 2];  // 64 KB fp16 x-tile

  const int tid = threadIdx.x;
  const int lane = tid & 63;
  const int wid = tid >> 6;  // head
  const int l15 = lane & 15;
  const int g = lane >> 4;
  const int b = blockIdx.x >> 3;
  const int ch = blockIdx.x & 7;

  const uint16_t* qwh = qw + wid * (64 * 512);
  const uint16_t* wvh = wv + wid * (64 * 512);
  const float* xbase = x + ((size_t)b * 4096 + (size_t)ch * 512) * 512;

  const f32x4 vzero = {0.f, 0.f, 0.f, 0.f};
  f32x4 acco[4][4];
#pragma unroll
  for (int i = 0; i < 4; ++i)
#pragma unroll
    for (int j = 0; j < 4; ++j) acco[i][j] = vzero;
  float Mst[4] = {-1e30f, -1e30f, -1e30f, -1e30f};
  float Lst[4] = {0.f, 0.f, 0.f, 0.f};

  const int s0 = l15 + (g & 1) * 32;  // shuffle source base for P/V re-layout
  const bool selhi = (lane >= 32);

  // ---- prologue: prefetch tile 0 into registers (2 x 8 float4)
  float4 pfA[8], pfB[8];
#pragma unroll
  for (int it = 0; it < 8; ++it)
    pfA[it] = *reinterpret_cast<const float4*>(xbase + it * 2048 + tid * 4);
#pragma unroll
  for (int it = 0; it < 8; ++it)
    pfB[it] =
        *reinterpret_cast<const float4*>(xbase + 16384 + it * 2048 + tid * 4);

  for (int mt = 0; mt < 8; ++mt) {
    __syncthreads();  // all waves done reading previous tile's xs
    // ---- write prefetched tile: fp32 -> fp16, swizzle ^((row&7)<<4)
#pragma unroll
    for (int it = 0; it < 16; ++it) {
      int e = it * 2048 + tid * 4;
      float4 v = (it < 8) ? pfA[it] : pfB[it - 8];
      int row = e >> 9;
      int byte = (e * 2) ^ ((row & 7) << 4);
      uint2 p;
      p.x = packh2(v.x, v.y);
      p.y = packh2(v.z, v.w);
      *reinterpret_cast<uint2*>(xs + byte) = p;
    }
    __syncthreads();

    // ---- S GEMM: accs[mi][wi] = x_tile @ QW_h^T  (64m x 64w, K=512)
    f32x4 accs[4][4];
#pragma unroll
    for (int i = 0; i < 4; ++i)
#pragma unroll
      for (int j = 0; j < 4; ++j) accs[i][j] = vzero;
#pragma unroll
    for (int kk = 0; kk < 16; ++kk) {
      half8 a[4];
#pragma unroll
      for (int mi = 0; mi < 4; ++mi) {
        int row = mi * 16 + l15;
        int byte = (row * 1024 + kk * 64 + g * 16) ^ ((row & 7) << 4);
        a[mi] = *reinterpret_cast<const half8*>(xs + byte);
      }
#pragma unroll
      for (int wi = 0; wi < 4; ++wi) {
        half8 bq = *reinterpret_cast<const half8*>(
            qwh + (wi * 16 + l15) * 512 + kk * 32 + g * 8);
#pragma unroll
        for (int mi = 0; mi < 4; ++mi)
          accs[mi][wi] = __builtin_amdgcn_mfma_f32_16x16x32_f16(
              a[mi], bq, accs[mi][wi], 0, 0, 0);
      }
    }

    // ---- async-STAGE half 1 (low-pressure window: accs live, p2/accv not):
    // loads stay in flight through softmax + V GEMM + PV.
    if (mt < 7) {
      const float* xn = xbase + (mt + 1) * 32768;
#pragma unroll
      for (int it = 0; it < 8; ++it)
        pfA[it] = *reinterpret_cast<const float4*>(xn + it * 2048 + tid * 4);
    }

    // ---- online softmax over m (columns of S per fixed w = 16*wi + l15)
    uint32_t p2[4][4][2];
#pragma unroll
    for (int wi = 0; wi < 4; ++wi) {
      float tmax = -1e30f;
#pragma unroll
      for (int mi = 0; mi < 4; ++mi) {
        tmax = fmaxf(tmax, fmaxf(fmaxf(accs[mi][wi][0], accs[mi][wi][1]),
                                 fmaxf(accs[mi][wi][2], accs[mi][wi][3])));
      }
      tmax = fmaxf(tmax, __shfl_xor(tmax, 16));
      tmax = fmaxf(tmax, __shfl_xor(tmax, 32));
      float newM = fmaxf(Mst[wi], tmax);
      float sc = __expf(Mst[wi] - newM);
      Mst[wi] = newM;
      float tsum = 0.f;
#pragma unroll
      for (int mi = 0; mi < 4; ++mi) {
        float e0 = __expf(accs[mi][wi][0] - newM);
        float e1 = __expf(accs[mi][wi][1] - newM);
        float e2 = __expf(accs[mi][wi][2] - newM);
        float e3 = __expf(accs[mi][wi][3] - newM);
        tsum += (e0 + e1) + (e2 + e3);
        p2[mi][wi][0] = packh2(e0, e1);
        p2[mi][wi][1] = packh2(e2, e3);
      }
      tsum += __shfl_xor(tsum, 16);
      tsum += __shfl_xor(tsum, 32);
      Lst[wi] = Lst[wi] * sc + tsum;
      // rescale acco row-block wi: rows w = 16*wi + 4g + r; sc lives at lanes
      // with l15 == 4g+r  -> pick src lane 16g + 4g + r = 20g + r
#pragma unroll
      for (int r = 0; r < 4; ++r) {
        float scr = __shfl(sc, g * 20 + r);
#pragma unroll
        for (int nj = 0; nj < 4; ++nj) acco[wi][nj][r] *= scr;
      }
    }

    // ---- V GEMM: accv[mi][nj] = x_tile @ WV_h^T  (64m x 64j, K=512)
    f32x4 accv[4][4];
#pragma unroll
    for (int i = 0; i < 4; ++i)
#pragma unroll
      for (int j = 0; j < 4; ++j) accv[i][j] = vzero;
#pragma unroll
    for (int kk = 0; kk < 16; ++kk) {
      half8 a[4];
#pragma unroll
      for (int mi = 0; mi < 4; ++mi) {
        int row = mi * 16 + l15;
        int byte = (row * 1024 + kk * 64 + g * 16) ^ ((row & 7) << 4);
        a[mi] = *reinterpret_cast<const half8*>(xs + byte);
      }
#pragma unroll
      for (int nj = 0; nj < 4; ++nj) {
        half8 bv = *reinterpret_cast<const half8*>(
            wvh + (nj * 16 + l15) * 512 + kk * 32 + g * 8);
#pragma unroll
        for (int mi = 0; mi < 4; ++mi)
          accv[mi][nj] = __builtin_amdgcn_mfma_f32_16x16x32_f16(
              a[mi], bv, accv[mi][nj], 0, 0, 0);
      }
    }

    // ---- pack V to fp16 pairs (C-layout regs (r0,r1),(r2,r3)); accv dies
    uint32_t v2[4][4][2];
#pragma unroll
    for (int mi = 0; mi < 4; ++mi)
#pragma unroll
      for (int nj = 0; nj < 4; ++nj) {
        v2[mi][nj][0] = packh2(accv[mi][nj][0], accv[mi][nj][1]);
        v2[mi][nj][1] = packh2(accv[mi][nj][2], accv[mi][nj][3]);
      }

    // ---- async-STAGE half 2 (accv dead; covered by PV + barrier + half-1
    // staging writes of next iteration)
    if (mt < 7) {
      const float* xn = xbase + (mt + 1) * 32768;
#pragma unroll
      for (int it = 0; it < 8; ++it)
        pfB[it] = *reinterpret_cast<const float4*>(xn + 16384 + it * 2048 +
                                                   tid * 4);
    }

    // ---- PV: acco[w][j] += P^T @ V  via register re-layout shuffles
#pragma unroll
    for (int kk = 0; kk < 2; ++kk) {
      union { uint32_t u[4]; half8 s; } af[4], bfv[4];
#pragma unroll
      for (int i = 0; i < 4; ++i) {
        af[i].u[0] = selshfl(p2[2 * kk][i][0], p2[2 * kk + 1][i][0], s0, selhi);
        af[i].u[1] = selshfl(p2[2 * kk][i][1], p2[2 * kk + 1][i][1], s0, selhi);
        af[i].u[2] = selshfl(p2[2 * kk][i][0], p2[2 * kk + 1][i][0], s0 + 16, selhi);
        af[i].u[3] = selshfl(p2[2 * kk][i][1], p2[2 * kk + 1][i][1], s0 + 16, selhi);
        bfv[i].u[0] = selshfl(v2[2 * kk][i][0], v2[2 * kk + 1][i][0], s0, selhi);
        bfv[i].u[1] = selshfl(v2[2 * kk][i][1], v2[2 * kk + 1][i][1], s0, selhi);
        bfv[i].u[2] = selshfl(v2[2 * kk][i][0], v2[2 * kk + 1][i][0], s0 + 16, selhi);
        bfv[i].u[3] = selshfl(v2[2 * kk][i][1], v2[2 * kk + 1][i][1], s0 + 16, selhi);
      }
#pragma unroll
      for (int wi = 0; wi < 4; ++wi)
#pragma unroll
        for (int nj = 0; nj < 4; ++nj)
          acco[wi][nj] = __builtin_amdgcn_mfma_f32_16x16x32_f16(
              af[wi].s, bfv[nj].s, acco[wi][nj], 0, 0, 0);
    }
  }

  // ---- write flash partials for (b, ch, head)
  const size_t pbase = ((size_t)(b * 8 + ch) * 8 + wid) * 64;
#pragma unroll
  for (int wi = 0; wi < 4; ++wi) {
#pragma unroll
    for (int r = 0; r < 4; ++r) {
      int w = wi * 16 + g * 4 + r;
#pragma unroll
      for (int nj = 0; nj < 4; ++nj)
        pacc[(pbase + w) * 64 + nj * 16 + l15] = acco[wi][nj][r];
    }
  }
  if (g == 0) {
#pragma unroll
    for (int wi = 0; wi < 4; ++wi) {
      pm[pbase + wi * 16 + l15] = Mst[wi];
      pl[pbase + wi * 16 + l15] = Lst[wi];
    }
  }
}

// ---------------------------------------------------------------------------
// Kernel 2a: flash combine across the 8 m-chunks -> new_v fp16 (+v bias).
// Grid 512 x 512: thread = (b,h,w,jq); reads 8 chunk partials, writes 4 fp16.
// Streaming, coalesced float4 reads of pacc (33.5 MB total ~ 6 us).
// ---------------------------------------------------------------------------
__global__ __launch_bounds__(512) void combine_kernel(
    const float* __restrict__ pacc, const float* __restrict__ pm,
    const float* __restrict__ pl, const float* __restrict__ fc_b,
    uint16_t* __restrict__ nv /* [32][64][512] fp16, e = h*64+j */) {
  int t = blockIdx.x * 512 + threadIdx.x;   // 262144 = 32*8*64*16
  int jq = t & 15;
  int w = (t >> 4) & 63;
  int h = (t >> 10) & 7;
  int b = t >> 13;

  float pmv[8], fac[8];
  float mg = -1e30f;
#pragma unroll
  for (int c = 0; c < 8; ++c) {
    pmv[c] = pm[(((size_t)(b * 8 + c) * 8 + h) << 6) + w];
    mg = fmaxf(mg, pmv[c]);
  }
  float lg = 0.f;
#pragma unroll
  for (int c = 0; c < 8; ++c) {
    fac[c] = __expf(pmv[c] - mg);
    lg += pl[(((size_t)(b * 8 + c) * 8 + h) << 6) + w] * fac[c];
  }
  float inv = 1.0f / lg;
#pragma unroll
  for (int c = 0; c < 8; ++c) fac[c] *= inv;

  float s0 = 0.f, s1 = 0.f, s2 = 0.f, s3 = 0.f;
#pragma unroll
  for (int c = 0; c < 8; ++c) {
    const float4 a = *reinterpret_cast<const float4*>(
        &pacc[(((((size_t)(b * 8 + c) * 8 + h) << 6) + w) << 6) + jq * 4]);
    s0 += a.x * fac[c];
    s1 += a.y * fac[c];
    s2 += a.z * fac[c];
    s3 += a.w * fac[c];
  }
  int jb = h * 128 + 64 + jq * 4;  // deferred v-bias (sum att = 1)
  s0 += fc_b[jb + 0];
  s1 += fc_b[jb + 1];
  s2 += fc_b[jb + 2];
  s3 += fc_b[jb + 3];
  uint2 p;
  p.x = packh2(s0, s1);
  p.y = packh2(s2, s3);
  *reinterpret_cast<uint2*>(&nv[(size_t)(b * 64 + w) * 512 + h * 64 + jq * 4]) = p;
}

// ---------------------------------------------------------------------------
// Kernel 2b: out = new_v @ fc2^T + fcfc_b -> layernorm -> d_out (fp32).
// Grid 32 (one per b), 512 threads (8 waves; wave = 64-col d-slice).
// ---------------------------------------------------------------------------
__global__ __launch_bounds__(512) void gemmln_kernel(
    const uint16_t* __restrict__ nv, const uint16_t* __restrict__ fc2,
    const float* __restrict__ fcfc_b, float* __restrict__ out) {
  __shared__ __align__(16) uint8_t anv[64 * 512 * 2];  // new_v fp16 [w][e]
  __shared__ float red0[8][64];
  __shared__ float red1[8][64];

  const int tid = threadIdx.x;
  const int lane = tid & 63;
  const int wid = tid >> 6;
  const int l15 = lane & 15;
  const int g = lane >> 4;
  const int b = blockIdx.x;

  // stage new_v[b] (64 KB) into swizzled LDS: 8 x 16B per thread
  const uint8_t* nvb = reinterpret_cast<const uint8_t*>(nv) + (size_t)b * 65536;
#pragma unroll
  for (int it = 0; it < 8; ++it) {
    int o = it * 8192 + tid * 16;
    uint4 v = *reinterpret_cast<const uint4*>(nvb + o);
    int row = o >> 10;
    *reinterpret_cast<uint4*>(anv + (o ^ ((row & 7) << 4))) = v;
  }
  __syncthreads();

  // GEMM: acc[mi][nj] = new_v(64w x 512e) @ fc2^T, wave covers d-slice wid*64
  const f32x4 vzero = {0.f, 0.f, 0.f, 0.f};
  f32x4 acc[4][4];
#pragma unroll
  for (int i = 0; i < 4; ++i)
#pragma unroll
    for (int j = 0; j < 4; ++j) acc[i][j] = vzero;
#pragma unroll
  for (int kk = 0; kk < 16; ++kk) {
    half8 a[4];
#pragma unroll
    for (int mi = 0; mi < 4; ++mi) {
      int row = mi * 16 + l15;
      int byte = (row * 1024 + kk * 64 + g * 16) ^ ((row & 7) << 4);
      a[mi] = *reinterpret_cast<const half8*>(anv + byte);
    }
#pragma unroll
    for (int nj = 0; nj < 4; ++nj) {
      half8 bb = *reinterpret_cast<const half8*>(
          fc2 + (wid * 64 + nj * 16 + l15) * 512 + kk * 32 + g * 8);
#pragma unroll
      for (int mi = 0; mi < 4; ++mi)
        acc[mi][nj] =
            __builtin_amdgcn_mfma_f32_16x16x32_f16(a[mi], bb, acc[mi][nj], 0, 0, 0);
    }
  }
  // + fcfc bias
#pragma unroll
  for (int nj = 0; nj < 4; ++nj) {
    float bv = fcfc_b[wid * 64 + nj * 16 + l15];
#pragma unroll
    for (int mi = 0; mi < 4; ++mi)
#pragma unroll
      for (int r = 0; r < 4; ++r) acc[mi][nj][r] += bv;
  }
  // LN partial sums per row (this wave's 64 cols)
#pragma unroll
  for (int mi = 0; mi < 4; ++mi)
#pragma unroll
    for (int r = 0; r < 4; ++r) {
      float s = acc[mi][0][r] + acc[mi][1][r] + acc[mi][2][r] + acc[mi][3][r];
      float qq = acc[mi][0][r] * acc[mi][0][r] + acc[mi][1][r] * acc[mi][1][r] +
                 acc[mi][2][r] * acc[mi][2][r] + acc[mi][3][r] * acc[mi][3][r];
#pragma unroll
      for (int d = 1; d < 16; d <<= 1) {
        s += __shfl_xor(s, d);
        qq += __shfl_xor(qq, d);
      }
      if (l15 == 0) {
        int w = mi * 16 + g * 4 + r;
        red0[wid][w] = s;
        red1[wid][w] = qq;
      }
    }
  __syncthreads();
#pragma unroll
  for (int mi = 0; mi < 4; ++mi)
#pragma unroll
    for (int r = 0; r < 4; ++r) {
      int w = mi * 16 + g * 4 + r;
      float s = 0.f, qq = 0.f;
#pragma unroll
      for (int u = 0; u < 8; ++u) {
        s += red0[u][w];
        qq += red1[u][w];
      }
      float mean = s * (1.f / 512.f);
      float var = qq * (1.f / 512.f) - mean * mean;
      float rs = rsqrtf(var + EPS_LN);
#pragma unroll
      for (int nj = 0; nj < 4; ++nj) {
        int d = wid * 64 + nj * 16 + l15;
        out[((size_t)(b * 64 + w)) * 512 + d] = (acc[mi][nj][r] - mean) * rs;
      }
    }
}

// ---------------------------------------------------------------------------
// Workspace layout (bytes):
//   [0,        512K)   QW fp16  (8*64*512)
//   [512K,     1M  )   WV fp16
//   [1M,       1.5M)   FC2 fp16 (512*512)
//   [1.5M,     35.05M) pacc fp32 (32*8*8*64*64)
//   [+512K)            pm fp32
//   [+512K)            pl fp32
//   [+2M)              nv fp16 (32*64*512)      total ~38 MB
// ---------------------------------------------------------------------------
extern "C" void kernel_launch(void* const* d_in, const int* in_sizes, int n_in,
                              void* d_out, int out_size, void* d_ws,
                              size_t ws_size, hipStream_t stream) {
  (void)in_sizes; (void)n_in; (void)out_size; (void)ws_size;
  const float* x = (const float*)d_in[0];
  const float* q = (const float*)d_in[1];
  const float* fc_w = (const float*)d_in[2];
  const float* fc_b = (const float*)d_in[3];
  const float* fcfc_w = (const float*)d_in[4];
  const float* fcfc_b = (const float*)d_in[5];
  float* out = (float*)d_out;

  uint8_t* ws = (uint8_t*)d_ws;
  uint16_t* qw = (uint16_t*)(ws);
  uint16_t* wv = (uint16_t*)(ws + 524288);
  uint16_t* fc2 = (uint16_t*)(ws + 1048576);
  float* pacc = (float*)(ws + 1572864);
  float* pm = (float*)(ws + 1572864 + 33554432);
  float* pl = (float*)(ws + 1572864 + 33554432 + 524288);
  uint16_t* nv = (uint16_t*)(ws + 1572864 + 33554432 + 1048576);

  prep_kernel<<<1536, 512, 0, stream>>>(q, fc_w, fcfc_w, qw, wv, fc2);
  fused_attn<<<256, 512, 0, stream>>>(x, qw, wv, pacc, pm, pl);
  combine_kernel<<<512, 512, 0, stream>>>(pacc, pm, pl, fc_b, nv);
  gemmln_kernel<<<32, 512, 0, stream>>>(nv, fc2, fcfc_b, out);
}